// Round 9
// baseline (1305.197 us; speedup 1.0000x reference)
//
#include <hip/hip_runtime.h>
#include <hip/hip_bf16.h>

#define NEDGE 800000
#define NNODE 50000
#define DF    64
#define HID   128
#define NTILE (NEDGE / 16)

using short8 = __attribute__((ext_vector_type(8))) short;
using f32x4  = __attribute__((ext_vector_type(4))) float;
using i32x4  = __attribute__((ext_vector_type(4))) int;

union P8 { unsigned int u[4]; short8 s; };

__device__ __forceinline__ unsigned int pk2(float lo, float hi) {
    union { __hip_bfloat162 p; unsigned int u; } c;
    c.p = __float22bfloat162_rn(float2{lo, hi});
    return c.u;
}

__device__ __forceinline__ short8 cvt8(f32x4 u, f32x4 v) {
    P8 p;
    p.u[0] = pk2(u[0], u[1]);
    p.u[1] = pk2(u[2], u[3]);
    p.u[2] = pk2(v[0], v[1]);
    p.u[3] = pk2(v[2], v[3]);
    return p.s;
}

__device__ __forceinline__ unsigned short bf1(float f) {
    union { __hip_bfloat16 b; unsigned short u; } c;
    c.b = __float2bfloat16(f);
    return c.u;
}

__device__ __forceinline__ float silu_f(float v) {
    return v / (1.0f + __expf(-v));
}

// Fixed-point encode for packed-u64 atomic accumulation:
// field = u32(v * 2^15 + 2^24).  |v| < 512 guaranteed (actual |EO| < ~70),
// deg < 128 (Poisson(32)) -> low-field total < 2^32: no carry into high field.
#define FP_SCALE 32768.0f
#define FP_BIAS  16777216.0f
#define FP_BIASI 16777216u

__device__ __forceinline__ unsigned long long enc2(float va, float vb) {
    const unsigned int lo = (unsigned int)fmaf(va, FP_SCALE, FP_BIAS);
    const unsigned int hi = (unsigned int)fmaf(vb, FP_SCALE, FP_BIAS);
    return ((unsigned long long)hi << 32) | (unsigned long long)lo;
}

// XOR-swizzled byte offset inside a row-major [R][128]-bf16 tile (row stride 256B).
__device__ __forceinline__ int swz(int r, int k) {
    return (r << 8) + ((((k >> 3) ^ (r & 7)) << 4) | ((k & 7) << 1));
}
__device__ __forceinline__ int swz16(int r, int slot) {
    return (r << 8) + ((slot ^ (r & 7)) << 4);
}

// ==================== fused edge-MLP + packed u64 fixed-point scatter ===========
__global__ void __launch_bounds__(256, 2)
gnn_fused_q64(const float* __restrict__ x, const int* __restrict__ ei,
              const float* __restrict__ t,
              const float* __restrict__ W1, const float* __restrict__ b1,
              const float* __restrict__ Wt, const float* __restrict__ bt,
              const float* __restrict__ W2, const float* __restrict__ b2,
              unsigned long long* __restrict__ accq, unsigned int* __restrict__ deg)
{
    extern __shared__ char lds[];
    char* const w1s = lds;            // 32KB: W1^T bf16, swizzled, row = hidden j
    char* const w2s = lds + 32768;    // 32KB: W2^T bf16, swizzled, PERMUTED rows
    const int tid  = threadIdx.x;
    const int wave = tid >> 6;
    const int lane = tid & 63;
    char* const hs = lds + 65536 + (wave << 12);  // per-wave 4KB h tile

    // w2s permuted: row rho=((j&7)<<4)+(j>>3) so GEMM2 step nt at lane jl
    // yields output col jl*8+nt -> lane owns 8 ADJACENT cols (4 u64 pairs).
    for (int idx = tid; idx < HID * HID; idx += 256) {
        const int k = idx >> 7, j = idx & 127;
        *(unsigned short*)(w1s + swz(j, k)) = bf1(W1[idx]);
        const int rho = ((j & 7) << 4) + (j >> 3);
        *(unsigned short*)(w2s + swz(rho, k)) = bf1(W2[idx]);
    }

    const int jl   = lane & 15;
    const int quad = lane >> 4;
    const int k0   = quad << 3;
    float wtj[8], btj[8], b1j[8], b2j[8];
#pragma unroll
    for (int nt = 0; nt < 8; nt++) {
        const int j = nt * 16 + jl;
        wtj[nt] = Wt[j]; btj[nt] = bt[j]; b1j[nt] = b1[j];
        b2j[nt] = b2[jl * 8 + nt];           // permuted output col
    }
    __syncthreads();

    const int gwave = (blockIdx.x << 2) + wave;
    const int nwave = gridDim.x << 2;

#define ISSUE_EI(T, RA, CA) { const int e_ = (T) * 16 + jl; RA = ei[e_]; CA = ei[NEDGE + e_]; }
#define ISSUE_X(RA, CA, X_) { \
    const float* xr_ = x + (RA) * DF + k0; \
    const float* xc_ = x + (CA) * DF + k0; \
    X_[0] = *(const f32x4*)(xr_);      X_[1] = *(const f32x4*)(xr_ + 4);  \
    X_[2] = *(const f32x4*)(xr_ + 32); X_[3] = *(const f32x4*)(xr_ + 36); \
    X_[4] = *(const f32x4*)(xc_);      X_[5] = *(const f32x4*)(xc_ + 4);  \
    X_[6] = *(const f32x4*)(xc_ + 32); X_[7] = *(const f32x4*)(xc_ + 36); }
#define ISSUE_EP(T, T4_, RI_, CI_) { const int er_ = (T) * 16 + (quad << 2); \
    T4_ = *(const f32x4*)(t + er_); \
    RI_ = *(const i32x4*)(ei + er_); \
    CI_ = *(const i32x4*)(ei + NEDGE + er_); }

    // ---- pipeline prologue
    int tile = gwave;
    int riA, ciA;  ISSUE_EI(tile, riA, ciA);
    f32x4 X[8];    ISSUE_X(riA, ciA, X);
    f32x4 T4; i32x4 RI, CI; ISSUE_EP(tile, T4, RI, CI);
    int tn  = tile + nwave;
    int tns = (tn < NTILE) ? tn : gwave;
    int riA_n, ciA_n; ISSUE_EI(tns, riA_n, ciA_n);

    while (tile < NTILE) {
        // ---- prefetch t+1 (x, epilogue) and t+2 (edge indices)
        f32x4 Xn[8]; ISSUE_X(riA_n, ciA_n, Xn);
        f32x4 T4n; i32x4 RIn, CIn; ISSUE_EP(tns, T4n, RIn, CIn);
        const int t2  = tn + nwave;
        const int t2s = (t2 < NTILE) ? t2 : gwave;
        int riA_nn, ciA_nn; ISSUE_EI(t2s, riA_nn, ciA_nn);

        short8 a[4];
#pragma unroll
        for (int kk = 0; kk < 4; kk++) a[kk] = cvt8(X[2 * kk], X[2 * kk + 1]);

        // ---- GEMM1: h = silu(edge_in @ W1 + silu(t*Wt+bt) + b1) -> hs (bf16)
#pragma unroll
        for (int nt = 0; nt < 8; nt++) {
            f32x4 acc = {0.f, 0.f, 0.f, 0.f};
            const int j = nt * 16 + jl;
#pragma unroll
            for (int kk = 0; kk < 4; kk++) {
                const short8 bfr = *(const short8*)(w1s + swz16(j, (kk << 2) + quad));
                acc = __builtin_amdgcn_mfma_f32_16x16x32_bf16(a[kk], bfr, acc, 0, 0, 0);
            }
#pragma unroll
            for (int r = 0; r < 4; r++) {
                const float temb = silu_f(fmaf(T4[r], wtj[nt], btj[nt]));
                const float h = silu_f(acc[r] + temb + b1j[nt]);
                *(unsigned short*)(hs + swz((quad << 2) + r, j)) = bf1(h);
            }
        }

        short8 a2[4];
#pragma unroll
        for (int kk = 0; kk < 4; kk++) {
            a2[kk] = *(const short8*)(hs + swz16(jl, (kk << 2) + quad));
        }

        // ---- GEMM2 (permuted cols: lane jl owns cols jl*8 .. jl*8+7)
        f32x4 acc2[8];
#pragma unroll
        for (int nt = 0; nt < 8; nt++) {
            f32x4 acc = {0.f, 0.f, 0.f, 0.f};
            const int rho = nt * 16 + jl;
#pragma unroll
            for (int kk = 0; kk < 4; kk++) {
                const short8 bfr = *(const short8*)(w2s + swz16(rho, (kk << 2) + quad));
                acc = __builtin_amdgcn_mfma_f32_16x16x32_bf16(a2[kk], bfr, acc, 0, 0, 0);
            }
            acc2[nt] = acc;
        }

        // ---- u64 fixed-point atomic scatter: 4 RMW per (lane,row) for 8 cols
        // jl<8 -> cols 0..63 (src half, node=RI[r]); jl>=8 -> cols 64..127 (CI[r])
        // + 1 deg bump per (row,side) by one lane (bias removal in decode)
#pragma unroll
        for (int r = 0; r < 4; r++) {
            const int node = (jl < 8) ? RI[r] : CI[r];
            if (jl == 0) atomicAdd(&deg[RI[r]], 1u);
            if (jl == 8) atomicAdd(&deg[CI[r]], 1u);
            unsigned long long* p = accq + (size_t)node * 32 + ((jl & 7) << 2);
            atomicAdd(p + 0, enc2(acc2[0][r] + b2j[0], acc2[1][r] + b2j[1]));
            atomicAdd(p + 1, enc2(acc2[2][r] + b2j[2], acc2[3][r] + b2j[3]));
            atomicAdd(p + 2, enc2(acc2[4][r] + b2j[4], acc2[5][r] + b2j[5]));
            atomicAdd(p + 3, enc2(acc2[6][r] + b2j[6], acc2[7][r] + b2j[7]));
        }

        // ---- rotate pipeline state
        tile = tn; tn = t2; tns = t2s;
#pragma unroll
        for (int i = 0; i < 8; i++) X[i] = Xn[i];
        T4 = T4n; RI = RIn; CI = CIn;
        riA_n = riA_nn; ciA_n = ciA_nn;
    }
#undef ISSUE_EI
#undef ISSUE_X
#undef ISSUE_EP
}

// ==================== fixed-point accumulator -> f32 out ========================
__global__ void __launch_bounds__(256)
decode_kernel(const unsigned long long* __restrict__ accq,
              const unsigned int* __restrict__ deg, float2* __restrict__ out)
{
    const int i = blockIdx.x * 256 + threadIdx.x;   // over NNODE*32 pairs
    if (i < NNODE * 32) {
        const unsigned long long v = accq[i];
        const unsigned int bias = deg[i >> 5] * FP_BIASI;
        const int lo = (int)((unsigned int)v - bias);          // wrap-safe signed
        const int hi = (int)((unsigned int)(v >> 32) - bias);
        out[i] = float2{lo * (1.0f / FP_SCALE), hi * (1.0f / FP_SCALE)};
    }
}

extern "C" void kernel_launch(void* const* d_in, const int* in_sizes, int n_in,
                              void* d_out, int out_size, void* d_ws, size_t ws_size,
                              hipStream_t stream) {
    const float* x  = (const float*)d_in[0];
    const int*   ei = (const int*)d_in[1];
    const float* t  = (const float*)d_in[2];
    const float* W1 = (const float*)d_in[3];
    const float* b1 = (const float*)d_in[4];
    const float* Wt = (const float*)d_in[5];
    const float* bt = (const float*)d_in[6];
    const float* W2 = (const float*)d_in[7];
    const float* b2 = (const float*)d_in[8];
    float* out = (float*)d_out;

    unsigned long long* accq = (unsigned long long*)d_ws;          // 12.8 MB
    unsigned int* deg = (unsigned int*)(accq + (size_t)NNODE * 32); // 200 KB

    (void)hipMemsetAsync(d_ws, 0,
        (size_t)NNODE * 32 * sizeof(unsigned long long) + (size_t)NNODE * sizeof(unsigned int),
        stream);

    const int ldsBytes = 65536 + 4 * 4096;  // 80KB -> 2 blocks/CU
    (void)hipFuncSetAttribute((const void*)gnn_fused_q64,
                              hipFuncAttributeMaxDynamicSharedMemorySize, ldsBytes);
    hipLaunchKernelGGL(gnn_fused_q64, dim3(512), dim3(256), ldsBytes, stream,
                       x, ei, t, W1, b1, Wt, bt, W2, b2, accq, deg);

    hipLaunchKernelGGL(decode_kernel, dim3((NNODE * 32 + 255) / 256), dim3(256), 0, stream,
                       accq, deg, (float2*)out);
}

// Round 10
// 321.701 us; speedup vs baseline: 4.0572x; 4.0572x over previous
//
#include <hip/hip_runtime.h>
#include <hip/hip_bf16.h>

#define NEDGE 800000
#define NNODE 50000
#define DF    64
#define HID   128

using short8 = __attribute__((ext_vector_type(8))) short;
using f32x4  = __attribute__((ext_vector_type(4))) float;
using i32x4  = __attribute__((ext_vector_type(4))) int;

union P8 { unsigned int u[4]; short8 s; };

__device__ __forceinline__ unsigned int pk2(float lo, float hi) {
    union { __hip_bfloat162 p; unsigned int u; } c;
    c.p = __float22bfloat162_rn(float2{lo, hi});
    return c.u;
}

__device__ __forceinline__ short8 cvt8(f32x4 u, f32x4 v) {
    P8 p;
    p.u[0] = pk2(u[0], u[1]);
    p.u[1] = pk2(u[2], u[3]);
    p.u[2] = pk2(v[0], v[1]);
    p.u[3] = pk2(v[2], v[3]);
    return p.s;
}

__device__ __forceinline__ unsigned short bf1(float f) {
    union { __hip_bfloat16 b; unsigned short u; } c;
    c.b = __float2bfloat16(f);
    return c.u;
}

__device__ __forceinline__ float bf2f(unsigned short u) {
    union { unsigned int i; float f; } c;
    c.i = ((unsigned int)u) << 16;
    return c.f;
}

__device__ __forceinline__ float silu_f(float v) {
    return v / (1.0f + __expf(-v));
}

// XOR-swizzled byte offset inside a row-major [R][128]-bf16 tile (row stride 256B).
__device__ __forceinline__ int swz(int r, int k) {
    return (r << 8) + ((((k >> 3) ^ (r & 7)) << 4) | ((k & 7) << 1));
}
__device__ __forceinline__ int swz16(int r, int slot) {
    return (r << 8) + ((slot ^ (r & 7)) << 4);
}

// ===================== CSR offsets: hist + 3-kernel scan ========================
__global__ void __launch_bounds__(256) hist_kernel(const int* __restrict__ ei,
                                                   int* __restrict__ counts, int ech) {
    const int i = blockIdx.x * 256 + threadIdx.x;
    if (i < 2 * NEDGE) {
        const int e = (i < NEDGE) ? i : (i - NEDGE);
        atomicAdd(&counts[(e / ech) * NNODE + ei[i]], 1);
    }
}

__global__ void __launch_bounds__(1024) scan1_kernel(const int* __restrict__ counts,
                                                     int* __restrict__ offs,
                                                     int* __restrict__ bsum, int nbuck) {
    __shared__ int buf[1024];
    const int tid = threadIdx.x;
    const int gid = blockIdx.x * 1024 + tid;
    const int v = (gid < nbuck) ? counts[gid] : 0;
    buf[tid] = v;
    __syncthreads();
#pragma unroll
    for (int off = 1; off < 1024; off <<= 1) {
        const int u = (tid >= off) ? buf[tid - off] : 0;
        __syncthreads();
        buf[tid] += u;
        __syncthreads();
    }
    if (gid < nbuck) offs[gid] = buf[tid] - v;     // block-local exclusive
    if (tid == 1023) bsum[blockIdx.x] = buf[1023];
}

__global__ void __launch_bounds__(1024) scan2_kernel(int* __restrict__ bsum, int nb) {
    __shared__ int buf[1024];
    const int tid = threadIdx.x;
    const int v = (tid < nb) ? bsum[tid] : 0;
    buf[tid] = v;
    __syncthreads();
#pragma unroll
    for (int off = 1; off < 1024; off <<= 1) {
        const int u = (tid >= off) ? buf[tid - off] : 0;
        __syncthreads();
        buf[tid] += u;
        __syncthreads();
    }
    if (tid < nb) bsum[tid] = buf[tid] - v;
}

__global__ void __launch_bounds__(1024) scan3_kernel(int* __restrict__ offs,
                                                     const int* __restrict__ bsum, int nbuck) {
    const int gid = blockIdx.x * 1024 + threadIdx.x;
    if (gid < nbuck) offs[gid] += bsum[blockIdx.x];
    if (gid == 0) offs[nbuck] = 2 * NEDGE;   // total incidences (exact)
}

// ====== Pass 1: edge MLP chunk -> bf16 rows scattered DIRECTLY into CSR slots ====
__global__ void __launch_bounds__(256, 2)
gnn_mlp_scatter(const float* __restrict__ x, const int* __restrict__ ei,
                const float* __restrict__ t,
                const float* __restrict__ W1, const float* __restrict__ b1,
                const float* __restrict__ Wt, const float* __restrict__ bt,
                const float* __restrict__ W2, const float* __restrict__ b2,
                unsigned short* __restrict__ eout, int* __restrict__ cursor,
                int edgeBase, int ctiles, int cb, int chunkStart)
{
    extern __shared__ char lds[];
    char* const w1s = lds;            // 32KB: W1^T bf16, swizzled
    char* const w2s = lds + 32768;    // 32KB: W2^T bf16, swizzled, PERMUTED rows
    const int tid  = threadIdx.x;
    const int wave = tid >> 6;
    const int lane = tid & 63;
    char* const hs = lds + 65536 + (wave << 12);

    // w2s permuted: row rho=((j&7)<<4)+(j>>3) so GEMM2 step nt at lane jl
    // yields output col jl*8+nt -> lane owns 8 ADJACENT cols (one 16B store).
    for (int idx = tid; idx < HID * HID; idx += 256) {
        const int k = idx >> 7, j = idx & 127;
        *(unsigned short*)(w1s + swz(j, k)) = bf1(W1[idx]);
        const int rho = ((j & 7) << 4) + (j >> 3);
        *(unsigned short*)(w2s + swz(rho, k)) = bf1(W2[idx]);
    }

    const int jl   = lane & 15;
    const int quad = lane >> 4;
    const int k0   = quad << 3;
    float wtj[8], btj[8], b1j[8], b2j[8];
#pragma unroll
    for (int nt = 0; nt < 8; nt++) {
        const int j = nt * 16 + jl;
        wtj[nt] = Wt[j]; btj[nt] = bt[j]; b1j[nt] = b1[j];
        b2j[nt] = b2[jl * 8 + nt];           // permuted output col
    }
    __syncthreads();

    const int gwave = (blockIdx.x << 2) + wave;
    const int nwave = gridDim.x << 2;

#define ISSUE_EI(T, RA, CA) { const int e_ = edgeBase + (T) * 16 + jl; RA = ei[e_]; CA = ei[NEDGE + e_]; }
#define ISSUE_X(RA, CA, X_) { \
    const float* xr_ = x + (RA) * DF + k0; \
    const float* xc_ = x + (CA) * DF + k0; \
    X_[0] = *(const f32x4*)(xr_);      X_[1] = *(const f32x4*)(xr_ + 4);  \
    X_[2] = *(const f32x4*)(xr_ + 32); X_[3] = *(const f32x4*)(xr_ + 36); \
    X_[4] = *(const f32x4*)(xc_);      X_[5] = *(const f32x4*)(xc_ + 4);  \
    X_[6] = *(const f32x4*)(xc_ + 32); X_[7] = *(const f32x4*)(xc_ + 36); }
#define ISSUE_EP(T, T4_, RI_, CI_) { const int er_ = edgeBase + (T) * 16 + (quad << 2); \
    T4_ = *(const f32x4*)(t + er_); \
    RI_ = *(const i32x4*)(ei + er_); \
    CI_ = *(const i32x4*)(ei + NEDGE + er_); }

    // ---- pipeline prologue
    int tile = gwave;
    if (tile < ctiles) {
        int riA, ciA;  ISSUE_EI(tile, riA, ciA);
        f32x4 X[8];    ISSUE_X(riA, ciA, X);
        f32x4 T4; i32x4 RI, CI; ISSUE_EP(tile, T4, RI, CI);
        int tn  = tile + nwave;
        int tns = (tn < ctiles) ? tn : gwave;
        int riA_n, ciA_n; ISSUE_EI(tns, riA_n, ciA_n);

        while (tile < ctiles) {
            f32x4 Xn[8]; ISSUE_X(riA_n, ciA_n, Xn);
            f32x4 T4n; i32x4 RIn, CIn; ISSUE_EP(tns, T4n, RIn, CIn);
            const int t2  = tn + nwave;
            const int t2s = (t2 < ctiles) ? t2 : gwave;
            int riA_nn, ciA_nn; ISSUE_EI(t2s, riA_nn, ciA_nn);

            // ---- claim CSR slots: 2 fast u32 atomics per edge, broadcast via shfl
            int posS[4], posT[4];
            {
                unsigned int ps[4], pt[4];
#pragma unroll
                for (int r = 0; r < 4; r++) {
                    ps[r] = (jl == 0) ? atomicAdd((unsigned int*)&cursor[cb + RI[r]], 1u) : 0u;
                    pt[r] = (jl == 8) ? atomicAdd((unsigned int*)&cursor[cb + CI[r]], 1u) : 0u;
                }
#pragma unroll
                for (int r = 0; r < 4; r++) {
                    posS[r] = __shfl((int)ps[r], lane & 48);
                    posT[r] = __shfl((int)pt[r], (lane & 48) | 8);
                }
            }

            short8 a[4];
#pragma unroll
            for (int kk = 0; kk < 4; kk++) a[kk] = cvt8(X[2 * kk], X[2 * kk + 1]);

            // ---- GEMM1: h = silu(edge_in @ W1 + silu(t*Wt+bt) + b1) -> hs (bf16)
#pragma unroll
            for (int nt = 0; nt < 8; nt++) {
                f32x4 acc = {0.f, 0.f, 0.f, 0.f};
                const int j = nt * 16 + jl;
#pragma unroll
                for (int kk = 0; kk < 4; kk++) {
                    const short8 bfr = *(const short8*)(w1s + swz16(j, (kk << 2) + quad));
                    acc = __builtin_amdgcn_mfma_f32_16x16x32_bf16(a[kk], bfr, acc, 0, 0, 0);
                }
#pragma unroll
                for (int r = 0; r < 4; r++) {
                    const float temb = silu_f(fmaf(T4[r], wtj[nt], btj[nt]));
                    const float h = silu_f(acc[r] + temb + b1j[nt]);
                    *(unsigned short*)(hs + swz((quad << 2) + r, j)) = bf1(h);
                }
            }

            short8 a2[4];
#pragma unroll
            for (int kk = 0; kk < 4; kk++) {
                a2[kk] = *(const short8*)(hs + swz16(jl, (kk << 2) + quad));
            }

            // ---- GEMM2 (permuted cols: lane jl owns cols jl*8 .. jl*8+7)
            f32x4 acc2[8];
#pragma unroll
            for (int nt = 0; nt < 8; nt++) {
                f32x4 acc = {0.f, 0.f, 0.f, 0.f};
                const int rho = nt * 16 + jl;
#pragma unroll
                for (int kk = 0; kk < 4; kk++) {
                    const short8 bfr = *(const short8*)(w2s + swz16(rho, (kk << 2) + quad));
                    acc = __builtin_amdgcn_mfma_f32_16x16x32_bf16(a2[kk], bfr, acc, 0, 0, 0);
                }
                acc2[nt] = acc;
            }

            // ---- scatter rows into CSR slots: 128B contiguous (8 lanes x 16B)
#pragma unroll
            for (int r = 0; r < 4; r++) {
                const int pos   = (jl < 8) ? posS[r] : posT[r];
                const int local = pos - chunkStart;
                unsigned short* dst = eout + (size_t)local * 64 + ((jl & 7) << 3);
                P8 p;
                p.u[0] = pk2(acc2[0][r] + b2j[0], acc2[1][r] + b2j[1]);
                p.u[1] = pk2(acc2[2][r] + b2j[2], acc2[3][r] + b2j[3]);
                p.u[2] = pk2(acc2[4][r] + b2j[4], acc2[5][r] + b2j[5]);
                p.u[3] = pk2(acc2[6][r] + b2j[6], acc2[7][r] + b2j[7]);
                *(short8*)dst = p.s;
            }

            // ---- rotate pipeline state
            tile = tn; tn = t2; tns = t2s;
#pragma unroll
            for (int i = 0; i < 8; i++) X[i] = Xn[i];
            T4 = T4n; RI = RIn; CI = CIn;
            riA_n = riA_nn; ciA_n = ciA_nn;
        }
    }
#undef ISSUE_EI
#undef ISSUE_X
#undef ISSUE_EP
}

// ======= Pass 2: per-node gather; runs are CONTIGUOUS (CSR-ordered rows) ========
__global__ void __launch_bounds__(256)
gather_chunk(const unsigned short* __restrict__ eout, const int* __restrict__ offs,
             float* __restrict__ out, int cb, int chunkStart, int first)
{
    const int wave = threadIdx.x >> 6;
    const int lane = threadIdx.x & 63;
    const int n = blockIdx.x * 4 + wave;
    if (n >= NNODE) return;
    const int o0 = offs[cb + n] - chunkStart;
    const int o1 = offs[cb + n + 1] - chunkStart;

    const unsigned int* eb = (const unsigned int*)eout;  // 32 u32 per row
    const int fp = lane & 31;        // feature pair
    const int rp = lane >> 5;        // row parity
    float ax = 0.f, ay = 0.f;
    for (int k = o0 + rp; k < o1; k += 2) {
        const unsigned int w = eb[(size_t)k * 32 + fp];
        ax += bf2f((unsigned short)w);
        ay += bf2f((unsigned short)(w >> 16));
    }
    ax += __shfl_xor(ax, 32);
    ay += __shfl_xor(ay, 32);
    if (lane < 32) {
        float2* o2 = (float2*)out + (size_t)n * 32 + fp;
        const float2 prev = first ? float2{0.f, 0.f} : *o2;
        *o2 = float2{prev.x + ax, prev.y + ay};
    }
}

// ==================== Fallback: fused atomic version (R3, proven 372us) =========
__global__ void __launch_bounds__(256, 2)
gnn_fused_atomic(const float* __restrict__ x, const int* __restrict__ ei,
                 const float* __restrict__ t,
                 const float* __restrict__ W1, const float* __restrict__ b1,
                 const float* __restrict__ Wt, const float* __restrict__ bt,
                 const float* __restrict__ W2, const float* __restrict__ b2,
                 float* __restrict__ out)
{
    extern __shared__ char lds[];
    char* const w1s = lds;
    char* const w2s = lds + 32768;
    const int tid  = threadIdx.x;
    const int wave = tid >> 6;
    const int lane = tid & 63;
    char* const hs = lds + 65536 + (wave << 12);

    for (int idx = tid; idx < HID * HID; idx += 256) {
        const int k = idx >> 7, j = idx & 127;
        const int off = swz(j, k);
        *(unsigned short*)(w1s + off) = bf1(W1[idx]);
        *(unsigned short*)(w2s + off) = bf1(W2[idx]);
    }

    const int jl   = lane & 15;
    const int quad = lane >> 4;
    const int k0   = quad << 3;
    float wtj[8], btj[8], b1j[8], b2j[8];
#pragma unroll
    for (int nt = 0; nt < 8; nt++) {
        const int j = nt * 16 + jl;
        wtj[nt] = Wt[j]; btj[nt] = bt[j]; b1j[nt] = b1[j]; b2j[nt] = b2[j];
    }
    __syncthreads();

    const int gwave = (blockIdx.x << 2) + wave;
    const int nwave = gridDim.x << 2;

    for (int tile = gwave; tile < NEDGE / 16; tile += nwave) {
        const int base = tile << 4;
        const int eA = base + jl;
        const int ri = ei[eA];
        const int ci = ei[NEDGE + eA];

        short8 a[4];
        {
            const float* xr_ = x + ri * DF + k0;
            const float* xc_ = x + ci * DF + k0;
            a[0] = cvt8(*(const f32x4*)(xr_),      *(const f32x4*)(xr_ + 4));
            a[1] = cvt8(*(const f32x4*)(xr_ + 32), *(const f32x4*)(xr_ + 36));
            a[2] = cvt8(*(const f32x4*)(xc_),      *(const f32x4*)(xc_ + 4));
            a[3] = cvt8(*(const f32x4*)(xc_ + 32), *(const f32x4*)(xc_ + 36));
        }

        const int er = base + (quad << 2);
        const f32x4 T4 = *(const f32x4*)(t + er);
        const i32x4 RI = *(const i32x4*)(ei + er);
        const i32x4 CI = *(const i32x4*)(ei + NEDGE + er);

#pragma unroll
        for (int nt = 0; nt < 8; nt++) {
            f32x4 acc = {0.f, 0.f, 0.f, 0.f};
            const int j = nt * 16 + jl;
#pragma unroll
            for (int kk = 0; kk < 4; kk++) {
                const short8 bfr = *(const short8*)(w1s + swz16(j, (kk << 2) + quad));
                acc = __builtin_amdgcn_mfma_f32_16x16x32_bf16(a[kk], bfr, acc, 0, 0, 0);
            }
#pragma unroll
            for (int r = 0; r < 4; r++) {
                const float temb = silu_f(fmaf(T4[r], wtj[nt], btj[nt]));
                const float h = silu_f(acc[r] + temb + b1j[nt]);
                *(unsigned short*)(hs + swz((quad << 2) + r, j)) = bf1(h);
            }
        }

        short8 a2[4];
#pragma unroll
        for (int kk = 0; kk < 4; kk++) {
            a2[kk] = *(const short8*)(hs + swz16(jl, (kk << 2) + quad));
        }

#pragma unroll
        for (int nt = 0; nt < 8; nt++) {
            f32x4 acc = {0.f, 0.f, 0.f, 0.f};
            const int j = nt * 16 + jl;
#pragma unroll
            for (int kk = 0; kk < 4; kk++) {
                const short8 bfr = *(const short8*)(w2s + swz16(j, (kk << 2) + quad));
                acc = __builtin_amdgcn_mfma_f32_16x16x32_bf16(a2[kk], bfr, acc, 0, 0, 0);
            }
#pragma unroll
            for (int r = 0; r < 4; r++) {
                const float v = acc[r] + b2j[nt];
                const int node = (nt < 4) ? RI[r] : CI[r];
                unsafeAtomicAdd(out + node * DF + (j & 63), v);
            }
        }
    }
}

extern "C" void kernel_launch(void* const* d_in, const int* in_sizes, int n_in,
                              void* d_out, int out_size, void* d_ws, size_t ws_size,
                              hipStream_t stream) {
    const float* x  = (const float*)d_in[0];
    const int*   ei = (const int*)d_in[1];
    const float* t  = (const float*)d_in[2];
    const float* W1 = (const float*)d_in[3];
    const float* b1 = (const float*)d_in[4];
    const float* Wt = (const float*)d_in[5];
    const float* bt = (const float*)d_in[6];
    const float* W2 = (const float*)d_in[7];
    const float* b2 = (const float*)d_in[8];
    float* out = (float*)d_out;

    const int ldsBytes = 65536 + 4 * 4096;  // 80KB -> 2 blocks/CU

    // adaptive chunk count: smallest nch whose footprint fits ws
    int nch = 0;
    size_t eoutB = 0, nbuck = 0;
    for (int c : {1, 2, 4, 8, 16}) {
        const size_t eb = (size_t)(2 * (NEDGE / c)) * 64 * sizeof(unsigned short);
        const size_t nb = (size_t)c * NNODE;
        const size_t need = eb + (3 * nb + 1 + 1024) * sizeof(int) + 256;
        if (need <= ws_size) { nch = c; eoutB = eb; nbuck = nb; break; }
    }

    if (nch > 0) {
        const int ech = NEDGE / nch;
        char* wsb = (char*)d_ws;
        unsigned short* eout = (unsigned short*)wsb;
        int* counts = (int*)(wsb + eoutB);
        int* offs   = counts + nbuck;          // nbuck+1
        int* bsum   = offs + nbuck + 1;        // 1024
        int* cursor = bsum + 1024;             // nbuck

        const int nsb = (int)((nbuck + 1023) / 1024);

        (void)hipMemsetAsync(counts, 0, nbuck * sizeof(int), stream);
        hipLaunchKernelGGL(hist_kernel, dim3((2 * NEDGE + 255) / 256), dim3(256), 0, stream,
                           ei, counts, ech);
        hipLaunchKernelGGL(scan1_kernel, dim3(nsb), dim3(1024), 0, stream,
                           counts, offs, bsum, (int)nbuck);
        hipLaunchKernelGGL(scan2_kernel, dim3(1), dim3(1024), 0, stream, bsum, nsb);
        hipLaunchKernelGGL(scan3_kernel, dim3(nsb), dim3(1024), 0, stream, offs, (int)nbuck ? bsum : bsum, (int)nbuck);
        (void)hipMemcpyAsync(cursor, offs, nbuck * sizeof(int),
                             hipMemcpyDeviceToDevice, stream);

        (void)hipFuncSetAttribute((const void*)gnn_mlp_scatter,
                                  hipFuncAttributeMaxDynamicSharedMemorySize, ldsBytes);
        for (int c = 0; c < nch; ++c) {
            hipLaunchKernelGGL(gnn_mlp_scatter, dim3(512), dim3(256), ldsBytes, stream,
                               x, ei, t, W1, b1, Wt, bt, W2, b2,
                               eout, cursor, c * ech, ech / 16, c * NNODE, 2 * ech * c);
            hipLaunchKernelGGL(gather_chunk, dim3((NNODE + 3) / 4), dim3(256), 0, stream,
                               eout, offs, out, c * NNODE, 2 * ech * c, (c == 0) ? 1 : 0);
        }
    } else {
        // fallback: fused atomic version (proven, ~372us)
        (void)hipMemsetAsync(out, 0, (size_t)out_size * sizeof(float), stream);
        (void)hipFuncSetAttribute((const void*)gnn_fused_atomic,
                                  hipFuncAttributeMaxDynamicSharedMemorySize, ldsBytes);
        hipLaunchKernelGGL(gnn_fused_atomic, dim3(512), dim3(256), ldsBytes, stream,
                           x, ei, t, W1, b1, Wt, bt, W2, b2, out);
    }
}

// Round 11
// 303.750 us; speedup vs baseline: 4.2969x; 1.0591x over previous
//
#include <hip/hip_runtime.h>
#include <hip/hip_bf16.h>

#define NEDGE 800000
#define NNODE 50000
#define DF    64
#define HID   128
#define NTILE (NEDGE / 16)

using short8 = __attribute__((ext_vector_type(8))) short;
using f32x4  = __attribute__((ext_vector_type(4))) float;
using i32x4  = __attribute__((ext_vector_type(4))) int;

union P8 { unsigned int u[4]; short8 s; };

__device__ __forceinline__ unsigned int pk2(float lo, float hi) {
    union { __hip_bfloat162 p; unsigned int u; } c;
    c.p = __float22bfloat162_rn(float2{lo, hi});
    return c.u;
}

__device__ __forceinline__ short8 cvt8(f32x4 u, f32x4 v) {
    P8 p;
    p.u[0] = pk2(u[0], u[1]);
    p.u[1] = pk2(u[2], u[3]);
    p.u[2] = pk2(v[0], v[1]);
    p.u[3] = pk2(v[2], v[3]);
    return p.s;
}

__device__ __forceinline__ unsigned short bf1(float f) {
    union { __hip_bfloat16 b; unsigned short u; } c;
    c.b = __float2bfloat16(f);
    return c.u;
}

__device__ __forceinline__ float bf2f(unsigned short u) {
    union { unsigned int i; float f; } c;
    c.i = ((unsigned int)u) << 16;
    return c.f;
}

// fast silu: v_exp + v_rcp + mul (vs ~12-inst IEEE div expansion)
__device__ __forceinline__ float silu_f(float v) {
    return __fdividef(v, 1.0f + __expf(-v));
}

// XOR-swizzled byte offset inside a row-major [R][128]-bf16 tile (row stride 256B).
__device__ __forceinline__ int swz(int r, int k) {
    return (r << 8) + ((((k >> 3) ^ (r & 7)) << 4) | ((k & 7) << 1));
}
__device__ __forceinline__ int swz16(int r, int slot) {
    return (r << 8) + ((slot ^ (r & 7)) << 4);
}

// ===================== CSR offsets: hist + 3-kernel scan ========================
__global__ void __launch_bounds__(256) hist_kernel(const int* __restrict__ ei,
                                                   int* __restrict__ counts) {
    const int i = blockIdx.x * 256 + threadIdx.x;
    if (i < 2 * NEDGE) atomicAdd(&counts[ei[i]], 1);
}

__global__ void __launch_bounds__(1024) scan1_kernel(const int* __restrict__ counts,
                                                     int* __restrict__ offs,
                                                     int* __restrict__ bsum) {
    __shared__ int buf[1024];
    const int tid = threadIdx.x;
    const int gid = blockIdx.x * 1024 + tid;
    const int v = (gid < NNODE) ? counts[gid] : 0;
    buf[tid] = v;
    __syncthreads();
#pragma unroll
    for (int off = 1; off < 1024; off <<= 1) {
        const int u = (tid >= off) ? buf[tid - off] : 0;
        __syncthreads();
        buf[tid] += u;
        __syncthreads();
    }
    if (gid < NNODE) offs[gid] = buf[tid] - v;     // block-local exclusive
    if (tid == 1023) bsum[blockIdx.x] = buf[1023];
}

__global__ void __launch_bounds__(1024) scan2_kernel(int* __restrict__ bsum, int nb) {
    __shared__ int buf[1024];
    const int tid = threadIdx.x;
    const int v = (tid < nb) ? bsum[tid] : 0;
    buf[tid] = v;
    __syncthreads();
#pragma unroll
    for (int off = 1; off < 1024; off <<= 1) {
        const int u = (tid >= off) ? buf[tid - off] : 0;
        __syncthreads();
        buf[tid] += u;
        __syncthreads();
    }
    if (tid < nb) bsum[tid] = buf[tid] - v;
}

// finalize offs, init cursor (no separate memcpy dispatch)
__global__ void __launch_bounds__(1024) scan3_kernel(int* __restrict__ offs,
                                                     const int* __restrict__ bsum,
                                                     int* __restrict__ cursor) {
    const int gid = blockIdx.x * 1024 + threadIdx.x;
    if (gid < NNODE) {
        const int o = offs[gid] + bsum[blockIdx.x];
        offs[gid] = o;
        cursor[gid] = o;
    }
    if (gid == 0) offs[NNODE] = 2 * NEDGE;
}

// ====== Pass 1: edge MLP -> bf16 rows scattered DIRECTLY into CSR slots =========
__global__ void __launch_bounds__(256, 2)
gnn_mlp_scatter(const float* __restrict__ x, const int* __restrict__ ei,
                const float* __restrict__ t,
                const float* __restrict__ W1, const float* __restrict__ b1,
                const float* __restrict__ Wt, const float* __restrict__ bt,
                const float* __restrict__ W2, const float* __restrict__ b2,
                unsigned short* __restrict__ eout, int* __restrict__ cursor)
{
    extern __shared__ char lds[];
    char* const w1s = lds;            // 32KB: W1^T bf16, swizzled
    char* const w2s = lds + 32768;    // 32KB: W2^T bf16, swizzled, PERMUTED rows
    const int tid  = threadIdx.x;
    const int wave = tid >> 6;
    const int lane = tid & 63;
    char* const hs = lds + 65536 + (wave << 12);

    // w2s permuted: row rho=((j&7)<<4)+(j>>3) so GEMM2 step nt at lane jl
    // yields output col jl*8+nt -> lane owns 8 ADJACENT cols (one 16B store).
    for (int idx = tid; idx < HID * HID; idx += 256) {
        const int k = idx >> 7, j = idx & 127;
        *(unsigned short*)(w1s + swz(j, k)) = bf1(W1[idx]);
        const int rho = ((j & 7) << 4) + (j >> 3);
        *(unsigned short*)(w2s + swz(rho, k)) = bf1(W2[idx]);
    }

    const int jl   = lane & 15;
    const int quad = lane >> 4;
    const int k0   = quad << 3;
    float wtj[8], btj[8], b1j[8], b2j[8];
#pragma unroll
    for (int nt = 0; nt < 8; nt++) {
        const int j = nt * 16 + jl;
        wtj[nt] = Wt[j]; btj[nt] = bt[j]; b1j[nt] = b1[j];
        b2j[nt] = b2[jl * 8 + nt];           // permuted output col
    }
    __syncthreads();

    const int gwave = (blockIdx.x << 2) + wave;
    const int nwave = gridDim.x << 2;

#define ISSUE_EI(T, RA, CA) { const int e_ = (T) * 16 + jl; RA = ei[e_]; CA = ei[NEDGE + e_]; }
#define ISSUE_X(RA, CA, X_) { \
    const float* xr_ = x + (RA) * DF + k0; \
    const float* xc_ = x + (CA) * DF + k0; \
    X_[0] = *(const f32x4*)(xr_);      X_[1] = *(const f32x4*)(xr_ + 4);  \
    X_[2] = *(const f32x4*)(xr_ + 32); X_[3] = *(const f32x4*)(xr_ + 36); \
    X_[4] = *(const f32x4*)(xc_);      X_[5] = *(const f32x4*)(xc_ + 4);  \
    X_[6] = *(const f32x4*)(xc_ + 32); X_[7] = *(const f32x4*)(xc_ + 36); }
#define ISSUE_EP(T, T4_, RI_, CI_) { const int er_ = (T) * 16 + (quad << 2); \
    T4_ = *(const f32x4*)(t + er_); \
    RI_ = *(const i32x4*)(ei + er_); \
    CI_ = *(const i32x4*)(ei + NEDGE + er_); }

    int tile = gwave;
    if (tile < NTILE) {
        int riA, ciA;  ISSUE_EI(tile, riA, ciA);
        f32x4 X[8];    ISSUE_X(riA, ciA, X);
        f32x4 T4; i32x4 RI, CI; ISSUE_EP(tile, T4, RI, CI);
        int tn  = tile + nwave;
        int tns = (tn < NTILE) ? tn : gwave;
        int riA_n, ciA_n; ISSUE_EI(tns, riA_n, ciA_n);

        while (tile < NTILE) {
            f32x4 Xn[8]; ISSUE_X(riA_n, ciA_n, Xn);
            f32x4 T4n; i32x4 RIn, CIn; ISSUE_EP(tns, T4n, RIn, CIn);
            const int t2  = tn + nwave;
            const int t2s = (t2 < NTILE) ? t2 : gwave;
            int riA_nn, ciA_nn; ISSUE_EI(t2s, riA_nn, ciA_nn);

            // ---- claim CSR slots: 2 fast u32 atomics per edge, broadcast via shfl
            int posS[4], posT[4];
            {
                unsigned int ps[4], pt[4];
#pragma unroll
                for (int r = 0; r < 4; r++) {
                    ps[r] = (jl == 0) ? atomicAdd((unsigned int*)&cursor[RI[r]], 1u) : 0u;
                    pt[r] = (jl == 8) ? atomicAdd((unsigned int*)&cursor[CI[r]], 1u) : 0u;
                }
#pragma unroll
                for (int r = 0; r < 4; r++) {
                    posS[r] = __shfl((int)ps[r], lane & 48);
                    posT[r] = __shfl((int)pt[r], (lane & 48) | 8);
                }
            }

            short8 a[4];
#pragma unroll
            for (int kk = 0; kk < 4; kk++) a[kk] = cvt8(X[2 * kk], X[2 * kk + 1]);

            // ---- GEMM1: h = silu(edge_in @ W1 + silu(t*Wt+bt) + b1) -> hs (bf16)
#pragma unroll
            for (int nt = 0; nt < 8; nt++) {
                f32x4 acc = {0.f, 0.f, 0.f, 0.f};
                const int j = nt * 16 + jl;
#pragma unroll
                for (int kk = 0; kk < 4; kk++) {
                    const short8 bfr = *(const short8*)(w1s + swz16(j, (kk << 2) + quad));
                    acc = __builtin_amdgcn_mfma_f32_16x16x32_bf16(a[kk], bfr, acc, 0, 0, 0);
                }
#pragma unroll
                for (int r = 0; r < 4; r++) {
                    const float temb = silu_f(fmaf(T4[r], wtj[nt], btj[nt]));
                    const float h = silu_f(acc[r] + temb + b1j[nt]);
                    *(unsigned short*)(hs + swz((quad << 2) + r, j)) = bf1(h);
                }
            }

            short8 a2[4];
#pragma unroll
            for (int kk = 0; kk < 4; kk++) {
                a2[kk] = *(const short8*)(hs + swz16(jl, (kk << 2) + quad));
            }

            // ---- GEMM2 (permuted cols: lane jl owns cols jl*8 .. jl*8+7)
            f32x4 acc2[8];
#pragma unroll
            for (int nt = 0; nt < 8; nt++) {
                f32x4 acc = {0.f, 0.f, 0.f, 0.f};
                const int rho = nt * 16 + jl;
#pragma unroll
                for (int kk = 0; kk < 4; kk++) {
                    const short8 bfr = *(const short8*)(w2s + swz16(rho, (kk << 2) + quad));
                    acc = __builtin_amdgcn_mfma_f32_16x16x32_bf16(a2[kk], bfr, acc, 0, 0, 0);
                }
                acc2[nt] = acc;
            }

            // ---- scatter rows into CSR slots: 128B contiguous (8 lanes x 16B)
#pragma unroll
            for (int r = 0; r < 4; r++) {
                const int pos = (jl < 8) ? posS[r] : posT[r];
                unsigned short* dst = eout + (size_t)pos * 64 + ((jl & 7) << 3);
                P8 p;
                p.u[0] = pk2(acc2[0][r] + b2j[0], acc2[1][r] + b2j[1]);
                p.u[1] = pk2(acc2[2][r] + b2j[2], acc2[3][r] + b2j[3]);
                p.u[2] = pk2(acc2[4][r] + b2j[4], acc2[5][r] + b2j[5]);
                p.u[3] = pk2(acc2[6][r] + b2j[6], acc2[7][r] + b2j[7]);
                *(short8*)dst = p.s;
            }

            // ---- rotate pipeline state
            tile = tn; tn = t2; tns = t2s;
#pragma unroll
            for (int i = 0; i < 8; i++) X[i] = Xn[i];
            T4 = T4n; RI = RIn; CI = CIn;
            riA_n = riA_nn; ciA_n = ciA_nn;
        }
    }
#undef ISSUE_EI
#undef ISSUE_X
#undef ISSUE_EP
}

// ======= Pass 2: per-node gather; 16B/lane loads, 8 rows (1KB) per iter =========
__global__ void __launch_bounds__(256)
gather_kernel(const unsigned short* __restrict__ eout, const int* __restrict__ offs,
              float* __restrict__ out)
{
    const int wave = threadIdx.x >> 6;
    const int lane = threadIdx.x & 63;
    const int n = blockIdx.x * 4 + wave;
    if (n >= NNODE) return;
    const int o0 = offs[n], o1 = offs[n + 1];

    const int cg = lane & 7;     // column group (8 bf16 = 16B)
    const int rp = lane >> 3;    // row phase 0..7
    float acc[8] = {0.f, 0.f, 0.f, 0.f, 0.f, 0.f, 0.f, 0.f};
    for (int k = o0 + rp; k < o1; k += 8) {
        const short8 v = *(const short8*)(eout + (size_t)k * 64 + (cg << 3));
#pragma unroll
        for (int j = 0; j < 8; j++) acc[j] += bf2f((unsigned short)v[j]);
    }
#pragma unroll
    for (int j = 0; j < 8; j++) {
        acc[j] += __shfl_xor(acc[j], 8);
        acc[j] += __shfl_xor(acc[j], 16);
        acc[j] += __shfl_xor(acc[j], 32);
    }
    if (rp == 0) {
        float* o = out + (size_t)n * DF + (cg << 3);
        *(f32x4*)(o)     = f32x4{acc[0], acc[1], acc[2], acc[3]};
        *(f32x4*)(o + 4) = f32x4{acc[4], acc[5], acc[6], acc[7]};
    }
}

// ==================== Fallback: fused atomic version (R3, proven 372us) =========
__global__ void __launch_bounds__(256, 2)
gnn_fused_atomic(const float* __restrict__ x, const int* __restrict__ ei,
                 const float* __restrict__ t,
                 const float* __restrict__ W1, const float* __restrict__ b1,
                 const float* __restrict__ Wt, const float* __restrict__ bt,
                 const float* __restrict__ W2, const float* __restrict__ b2,
                 float* __restrict__ out)
{
    extern __shared__ char lds[];
    char* const w1s = lds;
    char* const w2s = lds + 32768;
    const int tid  = threadIdx.x;
    const int wave = tid >> 6;
    const int lane = tid & 63;
    char* const hs = lds + 65536 + (wave << 12);

    for (int idx = tid; idx < HID * HID; idx += 256) {
        const int k = idx >> 7, j = idx & 127;
        const int off = swz(j, k);
        *(unsigned short*)(w1s + off) = bf1(W1[idx]);
        *(unsigned short*)(w2s + off) = bf1(W2[idx]);
    }

    const int jl   = lane & 15;
    const int quad = lane >> 4;
    const int k0   = quad << 3;
    float wtj[8], btj[8], b1j[8], b2j[8];
#pragma unroll
    for (int nt = 0; nt < 8; nt++) {
        const int j = nt * 16 + jl;
        wtj[nt] = Wt[j]; btj[nt] = bt[j]; b1j[nt] = b1[j]; b2j[nt] = b2[j];
    }
    __syncthreads();

    const int gwave = (blockIdx.x << 2) + wave;
    const int nwave = gridDim.x << 2;

    for (int tile = gwave; tile < NTILE; tile += nwave) {
        const int base = tile << 4;
        const int eA = base + jl;
        const int ri = ei[eA];
        const int ci = ei[NEDGE + eA];

        short8 a[4];
        {
            const float* xr_ = x + ri * DF + k0;
            const float* xc_ = x + ci * DF + k0;
            a[0] = cvt8(*(const f32x4*)(xr_),      *(const f32x4*)(xr_ + 4));
            a[1] = cvt8(*(const f32x4*)(xr_ + 32), *(const f32x4*)(xr_ + 36));
            a[2] = cvt8(*(const f32x4*)(xc_),      *(const f32x4*)(xc_ + 4));
            a[3] = cvt8(*(const f32x4*)(xc_ + 32), *(const f32x4*)(xc_ + 36));
        }

        const int er = base + (quad << 2);
        const f32x4 T4 = *(const f32x4*)(t + er);
        const i32x4 RI = *(const i32x4*)(ei + er);
        const i32x4 CI = *(const i32x4*)(ei + NEDGE + er);

#pragma unroll
        for (int nt = 0; nt < 8; nt++) {
            f32x4 acc = {0.f, 0.f, 0.f, 0.f};
            const int j = nt * 16 + jl;
#pragma unroll
            for (int kk = 0; kk < 4; kk++) {
                const short8 bfr = *(const short8*)(w1s + swz16(j, (kk << 2) + quad));
                acc = __builtin_amdgcn_mfma_f32_16x16x32_bf16(a[kk], bfr, acc, 0, 0, 0);
            }
#pragma unroll
            for (int r = 0; r < 4; r++) {
                const float temb = silu_f(fmaf(T4[r], wtj[nt], btj[nt]));
                const float h = silu_f(acc[r] + temb + b1j[nt]);
                *(unsigned short*)(hs + swz((quad << 2) + r, j)) = bf1(h);
            }
        }

        short8 a2[4];
#pragma unroll
        for (int kk = 0; kk < 4; kk++) {
            a2[kk] = *(const short8*)(hs + swz16(jl, (kk << 2) + quad));
        }

#pragma unroll
        for (int nt = 0; nt < 8; nt++) {
            f32x4 acc = {0.f, 0.f, 0.f, 0.f};
            const int j = nt * 16 + jl;
#pragma unroll
            for (int kk = 0; kk < 4; kk++) {
                const short8 bfr = *(const short8*)(w2s + swz16(j, (kk << 2) + quad));
                acc = __builtin_amdgcn_mfma_f32_16x16x32_bf16(a2[kk], bfr, acc, 0, 0, 0);
            }
#pragma unroll
            for (int r = 0; r < 4; r++) {
                const float v = acc[r] + b2j[nt];
                const int node = (nt < 4) ? RI[r] : CI[r];
                unsafeAtomicAdd(out + node * DF + (j & 63), v);
            }
        }
    }
}

extern "C" void kernel_launch(void* const* d_in, const int* in_sizes, int n_in,
                              void* d_out, int out_size, void* d_ws, size_t ws_size,
                              hipStream_t stream) {
    const float* x  = (const float*)d_in[0];
    const int*   ei = (const int*)d_in[1];
    const float* t  = (const float*)d_in[2];
    const float* W1 = (const float*)d_in[3];
    const float* b1 = (const float*)d_in[4];
    const float* Wt = (const float*)d_in[5];
    const float* bt = (const float*)d_in[6];
    const float* W2 = (const float*)d_in[7];
    const float* b2 = (const float*)d_in[8];
    float* out = (float*)d_out;

    const int ldsBytes = 65536 + 4 * 4096;  // 80KB -> 2 blocks/CU

    const size_t eoutB = (size_t)(2 * NEDGE) * 64 * sizeof(unsigned short);  // 204.8 MB
    const size_t need  = eoutB + (size_t)(3 * NNODE + 1 + 1024) * sizeof(int) + 256;

    if (ws_size >= need) {
        char* wsb = (char*)d_ws;
        unsigned short* eout = (unsigned short*)wsb;
        int* counts = (int*)(wsb + eoutB);
        int* offs   = counts + NNODE;          // NNODE+1
        int* bsum   = offs + NNODE + 1;        // 1024
        int* cursor = bsum + 1024;             // NNODE

        const int nsb = (NNODE + 1023) / 1024;  // 49

        (void)hipMemsetAsync(counts, 0, (size_t)NNODE * sizeof(int), stream);
        hipLaunchKernelGGL(hist_kernel, dim3((2 * NEDGE + 255) / 256), dim3(256), 0, stream,
                           ei, counts);
        hipLaunchKernelGGL(scan1_kernel, dim3(nsb), dim3(1024), 0, stream,
                           counts, offs, bsum);
        hipLaunchKernelGGL(scan2_kernel, dim3(1), dim3(1024), 0, stream, bsum, nsb);
        hipLaunchKernelGGL(scan3_kernel, dim3(nsb), dim3(1024), 0, stream,
                           offs, bsum, cursor);

        (void)hipFuncSetAttribute((const void*)gnn_mlp_scatter,
                                  hipFuncAttributeMaxDynamicSharedMemorySize, ldsBytes);
        hipLaunchKernelGGL(gnn_mlp_scatter, dim3(512), dim3(256), ldsBytes, stream,
                           x, ei, t, W1, b1, Wt, bt, W2, b2, eout, cursor);

        hipLaunchKernelGGL(gather_kernel, dim3((NNODE + 3) / 4), dim3(256), 0, stream,
                           eout, offs, out);
    } else {
        // fallback: fused atomic version (proven, ~372us)
        (void)hipMemsetAsync(out, 0, (size_t)out_size * sizeof(float), stream);
        (void)hipFuncSetAttribute((const void*)gnn_fused_atomic,
                                  hipFuncAttributeMaxDynamicSharedMemorySize, ldsBytes);
        hipLaunchKernelGGL(gnn_fused_atomic, dim3(512), dim3(256), ldsBytes, stream,
                           x, ei, t, W1, b1, Wt, bt, W2, b2, out);
    }
}

// Round 12
// 256.671 us; speedup vs baseline: 5.0851x; 1.1834x over previous
//
#include <hip/hip_runtime.h>
#include <hip/hip_bf16.h>

#define NEDGE 800000
#define NNODE 50000
#define DF    64
#define HID   128
#define NTILE (NEDGE / 16)

using short8 = __attribute__((ext_vector_type(8))) short;
using f32x4  = __attribute__((ext_vector_type(4))) float;
using i32x4  = __attribute__((ext_vector_type(4))) int;

union P8 { unsigned int u[4]; short8 s; };

__device__ __forceinline__ unsigned int pk2(float lo, float hi) {
    union { __hip_bfloat162 p; unsigned int u; } c;
    c.p = __float22bfloat162_rn(float2{lo, hi});
    return c.u;
}

__device__ __forceinline__ short8 cvt8(f32x4 u, f32x4 v) {
    P8 p;
    p.u[0] = pk2(u[0], u[1]);
    p.u[1] = pk2(u[2], u[3]);
    p.u[2] = pk2(v[0], v[1]);
    p.u[3] = pk2(v[2], v[3]);
    return p.s;
}

__device__ __forceinline__ unsigned short bf1(float f) {
    union { __hip_bfloat16 b; unsigned short u; } c;
    c.b = __float2bfloat16(f);
    return c.u;
}

__device__ __forceinline__ float bf2f(unsigned short u) {
    union { unsigned int i; float f; } c;
    c.i = ((unsigned int)u) << 16;
    return c.f;
}

// HW transcendentals: __expf/__fdividef lower to multi-op software sequences
// without -ffast-math (R11: fdividef == IEEE div, zero delta). 1:1 asm instead.
__device__ __forceinline__ float exp2_hw(float x) {
    float r; asm("v_exp_f32 %0, %1" : "=v"(r) : "v"(x)); return r;
}
__device__ __forceinline__ float rcp_hw(float x) {
    float r; asm("v_rcp_f32 %0, %1" : "=v"(r) : "v"(x)); return r;
}
// silu = v * sigmoid(v): 5 VALU ops (2 trans), ~1ulp each, invisible under bf16.
__device__ __forceinline__ float silu_f(float v) {
    return v * rcp_hw(1.0f + exp2_hw(v * -1.44269504f));
}

// XOR-swizzled byte offset inside a row-major [R][128]-bf16 tile (row stride 256B).
__device__ __forceinline__ int swz(int r, int k) {
    return (r << 8) + ((((k >> 3) ^ (r & 7)) << 4) | ((k & 7) << 1));
}
__device__ __forceinline__ int swz16(int r, int slot) {
    return (r << 8) + ((slot ^ (r & 7)) << 4);
}

// ===================== CSR offsets: hist + 3-kernel scan ========================
__global__ void __launch_bounds__(256) hist_kernel(const int* __restrict__ ei,
                                                   int* __restrict__ counts) {
    const int i = blockIdx.x * 256 + threadIdx.x;
    if (i < 2 * NEDGE) atomicAdd(&counts[ei[i]], 1);
}

__global__ void __launch_bounds__(1024) scan1_kernel(const int* __restrict__ counts,
                                                     int* __restrict__ offs,
                                                     int* __restrict__ bsum) {
    __shared__ int buf[1024];
    const int tid = threadIdx.x;
    const int gid = blockIdx.x * 1024 + tid;
    const int v = (gid < NNODE) ? counts[gid] : 0;
    buf[tid] = v;
    __syncthreads();
#pragma unroll
    for (int off = 1; off < 1024; off <<= 1) {
        const int u = (tid >= off) ? buf[tid - off] : 0;
        __syncthreads();
        buf[tid] += u;
        __syncthreads();
    }
    if (gid < NNODE) offs[gid] = buf[tid] - v;     // block-local exclusive
    if (tid == 1023) bsum[blockIdx.x] = buf[1023];
}

__global__ void __launch_bounds__(1024) scan2_kernel(int* __restrict__ bsum, int nb) {
    __shared__ int buf[1024];
    const int tid = threadIdx.x;
    const int v = (tid < nb) ? bsum[tid] : 0;
    buf[tid] = v;
    __syncthreads();
#pragma unroll
    for (int off = 1; off < 1024; off <<= 1) {
        const int u = (tid >= off) ? buf[tid - off] : 0;
        __syncthreads();
        buf[tid] += u;
        __syncthreads();
    }
    if (tid < nb) bsum[tid] = buf[tid] - v;
}

// finalize offs, init cursor (no separate memcpy dispatch)
__global__ void __launch_bounds__(1024) scan3_kernel(int* __restrict__ offs,
                                                     const int* __restrict__ bsum,
                                                     int* __restrict__ cursor) {
    const int gid = blockIdx.x * 1024 + threadIdx.x;
    if (gid < NNODE) {
        const int o = offs[gid] + bsum[blockIdx.x];
        offs[gid] = o;
        cursor[gid] = o;
    }
    if (gid == 0) offs[NNODE] = 2 * NEDGE;
}

// ====== Pass 1: edge MLP -> bf16 rows scattered DIRECTLY into CSR slots =========
__global__ void __launch_bounds__(256, 2)
gnn_mlp_scatter(const float* __restrict__ x, const int* __restrict__ ei,
                const float* __restrict__ t,
                const float* __restrict__ W1, const float* __restrict__ b1,
                const float* __restrict__ Wt, const float* __restrict__ bt,
                const float* __restrict__ W2, const float* __restrict__ b2,
                unsigned short* __restrict__ eout, int* __restrict__ cursor)
{
    extern __shared__ char lds[];
    char* const w1s = lds;            // 32KB: W1^T bf16, swizzled
    char* const w2s = lds + 32768;    // 32KB: W2^T bf16, swizzled, PERMUTED rows
    const int tid  = threadIdx.x;
    const int wave = tid >> 6;
    const int lane = tid & 63;
    char* const hs = lds + 65536 + (wave << 12);

    // w2s permuted: row rho=((j&7)<<4)+(j>>3) so GEMM2 step nt at lane jl
    // yields output col jl*8+nt -> lane owns 8 ADJACENT cols (one 16B store).
    for (int idx = tid; idx < HID * HID; idx += 256) {
        const int k = idx >> 7, j = idx & 127;
        *(unsigned short*)(w1s + swz(j, k)) = bf1(W1[idx]);
        const int rho = ((j & 7) << 4) + (j >> 3);
        *(unsigned short*)(w2s + swz(rho, k)) = bf1(W2[idx]);
    }

    const int jl   = lane & 15;
    const int quad = lane >> 4;
    const int k0   = quad << 3;
    float wtj[8], btj[8], b1j[8], b2j[8];
#pragma unroll
    for (int nt = 0; nt < 8; nt++) {
        const int j = nt * 16 + jl;
        wtj[nt] = Wt[j]; btj[nt] = bt[j]; b1j[nt] = b1[j];
        b2j[nt] = b2[jl * 8 + nt];           // permuted output col
    }
    __syncthreads();

    const int gwave = (blockIdx.x << 2) + wave;
    const int nwave = gridDim.x << 2;

#define ISSUE_EI(T, RA, CA) { const int e_ = (T) * 16 + jl; RA = ei[e_]; CA = ei[NEDGE + e_]; }
#define ISSUE_X(RA, CA, X_) { \
    const float* xr_ = x + (RA) * DF + k0; \
    const float* xc_ = x + (CA) * DF + k0; \
    X_[0] = *(const f32x4*)(xr_);      X_[1] = *(const f32x4*)(xr_ + 4);  \
    X_[2] = *(const f32x4*)(xr_ + 32); X_[3] = *(const f32x4*)(xr_ + 36); \
    X_[4] = *(const f32x4*)(xc_);      X_[5] = *(const f32x4*)(xc_ + 4);  \
    X_[6] = *(const f32x4*)(xc_ + 32); X_[7] = *(const f32x4*)(xc_ + 36); }
#define ISSUE_EP(T, T4_, RI_, CI_) { const int er_ = (T) * 16 + (quad << 2); \
    T4_ = *(const f32x4*)(t + er_); \
    RI_ = *(const i32x4*)(ei + er_); \
    CI_ = *(const i32x4*)(ei + NEDGE + er_); }

    int tile = gwave;
    if (tile < NTILE) {
        int riA, ciA;  ISSUE_EI(tile, riA, ciA);
        f32x4 X[8];    ISSUE_X(riA, ciA, X);
        f32x4 T4; i32x4 RI, CI; ISSUE_EP(tile, T4, RI, CI);
        int tn  = tile + nwave;
        int tns = (tn < NTILE) ? tn : gwave;
        int riA_n, ciA_n; ISSUE_EI(tns, riA_n, ciA_n);

        while (tile < NTILE) {
            f32x4 Xn[8]; ISSUE_X(riA_n, ciA_n, Xn);
            f32x4 T4n; i32x4 RIn, CIn; ISSUE_EP(tns, T4n, RIn, CIn);
            const int t2  = tn + nwave;
            const int t2s = (t2 < NTILE) ? t2 : gwave;
            int riA_nn, ciA_nn; ISSUE_EI(t2s, riA_nn, ciA_nn);

            // ---- claim CSR slots: 2 fast u32 atomics per edge, broadcast via shfl
            int posS[4], posT[4];
            {
                unsigned int ps[4], pt[4];
#pragma unroll
                for (int r = 0; r < 4; r++) {
                    ps[r] = (jl == 0) ? atomicAdd((unsigned int*)&cursor[RI[r]], 1u) : 0u;
                    pt[r] = (jl == 8) ? atomicAdd((unsigned int*)&cursor[CI[r]], 1u) : 0u;
                }
#pragma unroll
                for (int r = 0; r < 4; r++) {
                    posS[r] = __shfl((int)ps[r], lane & 48);
                    posT[r] = __shfl((int)pt[r], (lane & 48) | 8);
                }
            }

            short8 a[4];
#pragma unroll
            for (int kk = 0; kk < 4; kk++) a[kk] = cvt8(X[2 * kk], X[2 * kk + 1]);

            // ---- GEMM1: h = silu(edge_in @ W1 + silu(t*Wt+bt) + b1) -> hs (bf16)
#pragma unroll
            for (int nt = 0; nt < 8; nt++) {
                f32x4 acc = {0.f, 0.f, 0.f, 0.f};
                const int j = nt * 16 + jl;
#pragma unroll
                for (int kk = 0; kk < 4; kk++) {
                    const short8 bfr = *(const short8*)(w1s + swz16(j, (kk << 2) + quad));
                    acc = __builtin_amdgcn_mfma_f32_16x16x32_bf16(a[kk], bfr, acc, 0, 0, 0);
                }
#pragma unroll
                for (int r = 0; r < 4; r++) {
                    const float temb = silu_f(fmaf(T4[r], wtj[nt], btj[nt]));
                    const float h = silu_f(acc[r] + temb + b1j[nt]);
                    *(unsigned short*)(hs + swz((quad << 2) + r, j)) = bf1(h);
                }
            }

            short8 a2[4];
#pragma unroll
            for (int kk = 0; kk < 4; kk++) {
                a2[kk] = *(const short8*)(hs + swz16(jl, (kk << 2) + quad));
            }

            // ---- GEMM2 (permuted cols: lane jl owns cols jl*8 .. jl*8+7)
            f32x4 acc2[8];
#pragma unroll
            for (int nt = 0; nt < 8; nt++) {
                f32x4 acc = {0.f, 0.f, 0.f, 0.f};
                const int rho = nt * 16 + jl;
#pragma unroll
                for (int kk = 0; kk < 4; kk++) {
                    const short8 bfr = *(const short8*)(w2s + swz16(rho, (kk << 2) + quad));
                    acc = __builtin_amdgcn_mfma_f32_16x16x32_bf16(a2[kk], bfr, acc, 0, 0, 0);
                }
                acc2[nt] = acc;
            }

            // ---- scatter rows into CSR slots: 128B contiguous (8 lanes x 16B)
#pragma unroll
            for (int r = 0; r < 4; r++) {
                const int pos = (jl < 8) ? posS[r] : posT[r];
                unsigned short* dst = eout + (size_t)pos * 64 + ((jl & 7) << 3);
                P8 p;
                p.u[0] = pk2(acc2[0][r] + b2j[0], acc2[1][r] + b2j[1]);
                p.u[1] = pk2(acc2[2][r] + b2j[2], acc2[3][r] + b2j[3]);
                p.u[2] = pk2(acc2[4][r] + b2j[4], acc2[5][r] + b2j[5]);
                p.u[3] = pk2(acc2[6][r] + b2j[6], acc2[7][r] + b2j[7]);
                *(short8*)dst = p.s;
            }

            // ---- rotate pipeline state
            tile = tn; tn = t2; tns = t2s;
#pragma unroll
            for (int i = 0; i < 8; i++) X[i] = Xn[i];
            T4 = T4n; RI = RIn; CI = CIn;
            riA_n = riA_nn; ciA_n = ciA_nn;
        }
    }
#undef ISSUE_EI
#undef ISSUE_X
#undef ISSUE_EP
}

// ======= Pass 2: per-node gather; 16B/lane loads, 8 rows (1KB) per iter =========
__global__ void __launch_bounds__(256)
gather_kernel(const unsigned short* __restrict__ eout, const int* __restrict__ offs,
              float* __restrict__ out)
{
    const int wave = threadIdx.x >> 6;
    const int lane = threadIdx.x & 63;
    const int n = blockIdx.x * 4 + wave;
    if (n >= NNODE) return;
    const int o0 = offs[n], o1 = offs[n + 1];

    const int cg = lane & 7;     // column group (8 bf16 = 16B)
    const int rp = lane >> 3;    // row phase 0..7
    float acc[8] = {0.f, 0.f, 0.f, 0.f, 0.f, 0.f, 0.f, 0.f};
    for (int k = o0 + rp; k < o1; k += 8) {
        const short8 v = *(const short8*)(eout + (size_t)k * 64 + (cg << 3));
#pragma unroll
        for (int j = 0; j < 8; j++) acc[j] += bf2f((unsigned short)v[j]);
    }
#pragma unroll
    for (int j = 0; j < 8; j++) {
        acc[j] += __shfl_xor(acc[j], 8);
        acc[j] += __shfl_xor(acc[j], 16);
        acc[j] += __shfl_xor(acc[j], 32);
    }
    if (rp == 0) {
        float* o = out + (size_t)n * DF + (cg << 3);
        *(f32x4*)(o)     = f32x4{acc[0], acc[1], acc[2], acc[3]};
        *(f32x4*)(o + 4) = f32x4{acc[4], acc[5], acc[6], acc[7]};
    }
}

// ==================== Fallback: fused atomic version (R3, proven 372us) =========
__global__ void __launch_bounds__(256, 2)
gnn_fused_atomic(const float* __restrict__ x, const int* __restrict__ ei,
                 const float* __restrict__ t,
                 const float* __restrict__ W1, const float* __restrict__ b1,
                 const float* __restrict__ Wt, const float* __restrict__ bt,
                 const float* __restrict__ W2, const float* __restrict__ b2,
                 float* __restrict__ out)
{
    extern __shared__ char lds[];
    char* const w1s = lds;
    char* const w2s = lds + 32768;
    const int tid  = threadIdx.x;
    const int wave = tid >> 6;
    const int lane = tid & 63;
    char* const hs = lds + 65536 + (wave << 12);

    for (int idx = tid; idx < HID * HID; idx += 256) {
        const int k = idx >> 7, j = idx & 127;
        const int off = swz(j, k);
        *(unsigned short*)(w1s + off) = bf1(W1[idx]);
        *(unsigned short*)(w2s + off) = bf1(W2[idx]);
    }

    const int jl   = lane & 15;
    const int quad = lane >> 4;
    const int k0   = quad << 3;
    float wtj[8], btj[8], b1j[8], b2j[8];
#pragma unroll
    for (int nt = 0; nt < 8; nt++) {
        const int j = nt * 16 + jl;
        wtj[nt] = Wt[j]; btj[nt] = bt[j]; b1j[nt] = b1[j]; b2j[nt] = b2[j];
    }
    __syncthreads();

    const int gwave = (blockIdx.x << 2) + wave;
    const int nwave = gridDim.x << 2;

    for (int tile = gwave; tile < NTILE; tile += nwave) {
        const int base = tile << 4;
        const int eA = base + jl;
        const int ri = ei[eA];
        const int ci = ei[NEDGE + eA];

        short8 a[4];
        {
            const float* xr_ = x + ri * DF + k0;
            const float* xc_ = x + ci * DF + k0;
            a[0] = cvt8(*(const f32x4*)(xr_),      *(const f32x4*)(xr_ + 4));
            a[1] = cvt8(*(const f32x4*)(xr_ + 32), *(const f32x4*)(xr_ + 36));
            a[2] = cvt8(*(const f32x4*)(xc_),      *(const f32x4*)(xc_ + 4));
            a[3] = cvt8(*(const f32x4*)(xc_ + 32), *(const f32x4*)(xc_ + 36));
        }

        const int er = base + (quad << 2);
        const f32x4 T4 = *(const f32x4*)(t + er);
        const i32x4 RI = *(const i32x4*)(ei + er);
        const i32x4 CI = *(const i32x4*)(ei + NEDGE + er);

#pragma unroll
        for (int nt = 0; nt < 8; nt++) {
            f32x4 acc = {0.f, 0.f, 0.f, 0.f};
            const int j = nt * 16 + jl;
#pragma unroll
            for (int kk = 0; kk < 4; kk++) {
                const short8 bfr = *(const short8*)(w1s + swz16(j, (kk << 2) + quad));
                acc = __builtin_amdgcn_mfma_f32_16x16x32_bf16(a[kk], bfr, acc, 0, 0, 0);
            }
#pragma unroll
            for (int r = 0; r < 4; r++) {
                const float temb = silu_f(fmaf(T4[r], wtj[nt], btj[nt]));
                const float h = silu_f(acc[r] + temb + b1j[nt]);
                *(unsigned short*)(hs + swz((quad << 2) + r, j)) = bf1(h);
            }
        }

        short8 a2[4];
#pragma unroll
        for (int kk = 0; kk < 4; kk++) {
            a2[kk] = *(const short8*)(hs + swz16(jl, (kk << 2) + quad));
        }

#pragma unroll
        for (int nt = 0; nt < 8; nt++) {
            f32x4 acc = {0.f, 0.f, 0.f, 0.f};
            const int j = nt * 16 + jl;
#pragma unroll
            for (int kk = 0; kk < 4; kk++) {
                const short8 bfr = *(const short8*)(w2s + swz16(j, (kk << 2) + quad));
                acc = __builtin_amdgcn_mfma_f32_16x16x32_bf16(a2[kk], bfr, acc, 0, 0, 0);
            }
#pragma unroll
            for (int r = 0; r < 4; r++) {
                const float v = acc[r] + b2j[nt];
                const int node = (nt < 4) ? RI[r] : CI[r];
                unsafeAtomicAdd(out + node * DF + (j & 63), v);
            }
        }
    }
}

extern "C" void kernel_launch(void* const* d_in, const int* in_sizes, int n_in,
                              void* d_out, int out_size, void* d_ws, size_t ws_size,
                              hipStream_t stream) {
    const float* x  = (const float*)d_in[0];
    const int*   ei = (const int*)d_in[1];
    const float* t  = (const float*)d_in[2];
    const float* W1 = (const float*)d_in[3];
    const float* b1 = (const float*)d_in[4];
    const float* Wt = (const float*)d_in[5];
    const float* bt = (const float*)d_in[6];
    const float* W2 = (const float*)d_in[7];
    const float* b2 = (const float*)d_in[8];
    float* out = (float*)d_out;

    const int ldsBytes = 65536 + 4 * 4096;  // 80KB -> 2 blocks/CU

    const size_t eoutB = (size_t)(2 * NEDGE) * 64 * sizeof(unsigned short);  // 204.8 MB
    const size_t need  = eoutB + (size_t)(3 * NNODE + 1 + 1024) * sizeof(int) + 256;

    if (ws_size >= need) {
        char* wsb = (char*)d_ws;
        unsigned short* eout = (unsigned short*)wsb;
        int* counts = (int*)(wsb + eoutB);
        int* offs   = counts + NNODE;          // NNODE+1
        int* bsum   = offs + NNODE + 1;        // 1024
        int* cursor = bsum + 1024;             // NNODE

        const int nsb = (NNODE + 1023) / 1024;  // 49

        (void)hipMemsetAsync(counts, 0, (size_t)NNODE * sizeof(int), stream);
        hipLaunchKernelGGL(hist_kernel, dim3((2 * NEDGE + 255) / 256), dim3(256), 0, stream,
                           ei, counts);
        hipLaunchKernelGGL(scan1_kernel, dim3(nsb), dim3(1024), 0, stream,
                           counts, offs, bsum);
        hipLaunchKernelGGL(scan2_kernel, dim3(1), dim3(1024), 0, stream, bsum, nsb);
        hipLaunchKernelGGL(scan3_kernel, dim3(nsb), dim3(1024), 0, stream,
                           offs, bsum, cursor);

        (void)hipFuncSetAttribute((const void*)gnn_mlp_scatter,
                                  hipFuncAttributeMaxDynamicSharedMemorySize, ldsBytes);
        hipLaunchKernelGGL(gnn_mlp_scatter, dim3(512), dim3(256), ldsBytes, stream,
                           x, ei, t, W1, b1, Wt, bt, W2, b2, eout, cursor);

        hipLaunchKernelGGL(gather_kernel, dim3((NNODE + 3) / 4), dim3(256), 0, stream,
                           eout, offs, out);
    } else {
        // fallback: fused atomic version (proven, ~372us)
        (void)hipMemsetAsync(out, 0, (size_t)out_size * sizeof(float), stream);
        (void)hipFuncSetAttribute((const void*)gnn_fused_atomic,
                                  hipFuncAttributeMaxDynamicSharedMemorySize, ldsBytes);
        hipLaunchKernelGGL(gnn_fused_atomic, dim3(512), dim3(256), ldsBytes, stream,
                           x, ei, t, W1, b1, Wt, bt, W2, b2, out);
    }
}